// Round 1
// baseline (715.814 us; speedup 1.0000x reference)
//
#include <hip/hip_runtime.h>

// Problem constants
constexpr int L  = 32;
constexpr int K  = 4;
constexpr int D  = 1024;
constexpr int QO = 1024;
constexpr int KV = 256;
constexpr int FF = 2816;

// Grid layout: longest blocks first, shortest last (tail packing).
//   [0, 2048)      : Wd   — 16 rows/block (4/wave), I=2816, 12 act vectors fused
//   [2048, 4096)   : Wq/Wo — 32 rows/block (8/wave), I=1024
//   [4096, 6144)   : Wk/Wv — 32 rows/block (8/wave), I=256
//   [6144, 7040)   : residual float4 copy
constexpr int WD_BLOCKS  = L * 64;             // 2048
constexpr int QO_BLOCKS  = L * 64;             // 2048
constexpr int KV_BLOCKS  = L * 64;             // 2048
constexpr int RES_F4     = L * 7 * K * D / 4;  // 229376
constexpr int RES_BLOCKS = RES_F4 / 256;       // 896
constexpr int TOTAL_BLOCKS = WD_BLOCKS + QO_BLOCKS + KV_BLOCKS + RES_BLOCKS;

// Barrier-free streaming dot: weights stream from HBM (the only big traffic),
// activations come straight from global and hit L1/L2 (per-layer act sets are
// 4-135 KB, shared by 32-64 blocks). No LDS, no __syncthreads anywhere ->
// no vmcnt(0) drains; every wave pipelines its weight loads independently.
template<int NCH, int NR, int NK>
__device__ __forceinline__ void dot_g(const float* __restrict__ w0, int rstride,
                                      const float* __restrict__ a0, int astride,
                                      int lane, float (&acc)[NK][NR])
{
    #pragma unroll
    for (int c = 0; c < NCH; ++c) {
        float4 a[NK];
        #pragma unroll
        for (int kk = 0; kk < NK; ++kk)
            a[kk] = *(const float4*)(a0 + kk * astride + c * 256 + lane * 4);
        #pragma unroll
        for (int rr = 0; rr < NR; ++rr) {
            float4 w = *(const float4*)(w0 + (size_t)rr * rstride + c * 256 + lane * 4);
            #pragma unroll
            for (int kk = 0; kk < NK; ++kk) {
                acc[kk][rr] = fmaf(w.x, a[kk].x, acc[kk][rr]);
                acc[kk][rr] = fmaf(w.y, a[kk].y, acc[kk][rr]);
                acc[kk][rr] = fmaf(w.z, a[kk].z, acc[kk][rr]);
                acc[kk][rr] = fmaf(w.w, a[kk].w, acc[kk][rr]);
            }
        }
    }
}

template<int NK, int NR>
__device__ __forceinline__ void butterfly(float (&acc)[NK][NR])
{
    #pragma unroll
    for (int kk = 0; kk < NK; ++kk)
        #pragma unroll
        for (int rr = 0; rr < NR; ++rr) {
            float v = acc[kk][rr];
            #pragma unroll
            for (int mask = 32; mask >= 1; mask >>= 1)
                v += __shfl_xor(v, mask, 64);
            acc[kk][rr] = v;
        }
}

// 112 VGPRs previously -> 16 waves/CU. Force the allocator to stay <=128 so
// the 12-act-register Wd path can't slip to 8 waves/CU.
__global__ __launch_bounds__(256, 4) void bse_kernel(
    const float* __restrict__ residual, const float* __restrict__ cq,
    const float* __restrict__ ck,       const float* __restrict__ cv,
    const float* __restrict__ co,       const float* __restrict__ cmlp,
    const float* __restrict__ Wq,       const float* __restrict__ Wk,
    const float* __restrict__ Wv,       const float* __restrict__ Wo,
    const float* __restrict__ Wd,       float* __restrict__ out)
{
    int bid  = blockIdx.x;
    int tid  = threadIdx.x;
    int lane = tid & 63;
    int wave = tid >> 6;

    if (bid < WD_BLOCKS) {
        // ---- Wd: I=2816, 16 rows/block, 4 rows/wave, all 12 act vectors ----
        int l   = bid >> 6;
        int sub = bid & 63;
        int d0  = sub * 16 + wave * 4;
        const float* wbase = Wd   + ((size_t)l * D + d0) * FF;
        const float* abase = cmlp + (size_t)l * 12 * FF;

        float acc[12][4] = {};
        #pragma unroll 1
        for (int c = 0; c < 11; ++c)
            dot_g<1, 4, 12>(wbase + c * 256, FF, abase + c * 256, FF, lane, acc);

        butterfly<12, 4>(acc);
        if (lane == 0) {
            #pragma unroll
            for (int kk = 0; kk < 12; ++kk) {
                int mp = kk >> 2, k = kk & 3;
                int m  = (mp == 0) ? 3 : (mp == 1) ? 4 : 6;
                int base = (((l * 7 + m) * 2 + 1) * K + k) * D + d0;
                *(float4*)&out[base] = make_float4(acc[kk][0], acc[kk][1], acc[kk][2], acc[kk][3]);
            }
        }
    } else if (bid < WD_BLOCKS + QO_BLOCKS) {
        // ---- Wq / Wo: I=1024, 32 rows/block, 8 rows/wave ----
        int idx  = bid - WD_BLOCKS;
        int l    = idx >> 6;
        int r    = idx & 63;
        bool isQ = r < 32;
        int  sub = r & 31;
        int  m   = isQ ? 0 : 5;
        const float* Wp = (isQ ? Wq : Wo) + (size_t)l * D * QO;
        const float* ap = (isQ ? cq : co) + (size_t)l * K * QO;

        int d0 = sub * 32 + wave * 8;
        float acc[4][8] = {};
        dot_g<4, 8, 4>(Wp + (size_t)d0 * QO, QO, ap, QO, lane, acc);

        butterfly<4, 8>(acc);
        if (lane == 0) {
            #pragma unroll
            for (int k = 0; k < 4; ++k) {
                int base = (((l * 7 + m) * 2 + 1) * K + k) * D + d0;
                *(float4*)&out[base]     = make_float4(acc[k][0], acc[k][1], acc[k][2], acc[k][3]);
                *(float4*)&out[base + 4] = make_float4(acc[k][4], acc[k][5], acc[k][6], acc[k][7]);
            }
        }
    } else if (bid < WD_BLOCKS + QO_BLOCKS + KV_BLOCKS) {
        // ---- Wk / Wv: I=256, 32 rows/block, 8 rows/wave, single chunk ----
        int idx  = bid - WD_BLOCKS - QO_BLOCKS;
        int l    = idx >> 6;
        int r    = idx & 63;
        bool isK = r < 32;
        int  sub = r & 31;
        int  m   = isK ? 1 : 2;
        const float* Wp = (isK ? Wk : Wv) + (size_t)l * D * KV;
        const float* ap = (isK ? ck : cv) + (size_t)l * K * KV;

        int d0 = sub * 32 + wave * 8;
        float acc[4][8] = {};
        dot_g<1, 8, 4>(Wp + (size_t)d0 * KV, KV, ap, KV, lane, acc);

        butterfly<4, 8>(acc);
        if (lane == 0) {
            #pragma unroll
            for (int k = 0; k < 4; ++k) {
                int base = (((l * 7 + m) * 2 + 1) * K + k) * D + d0;
                *(float4*)&out[base]     = make_float4(acc[k][0], acc[k][1], acc[k][2], acc[k][3]);
                *(float4*)&out[base + 4] = make_float4(acc[k][4], acc[k][5], acc[k][6], acc[k][7]);
            }
        }
    } else {
        // ---- Residual copy into s=0 slots, float4 coalesced ----
        int f = (bid - WD_BLOCKS - QO_BLOCKS - KV_BLOCKS) * 256 + tid;
        float4 v = ((const float4*)residual)[f];
        int d4   = f & 255;
        int rest = f >> 8;
        int k    = rest & 3;
        int lm   = rest >> 2;
        ((float4*)out)[(lm * 2 * K + k) * 256 + d4] = v;
    }
}

extern "C" void kernel_launch(void* const* d_in, const int* in_sizes, int n_in,
                              void* d_out, int out_size, void* d_ws, size_t ws_size,
                              hipStream_t stream) {
    const float* residual = (const float*)d_in[0];
    const float* cq   = (const float*)d_in[1];
    const float* ck   = (const float*)d_in[2];
    const float* cv   = (const float*)d_in[3];
    const float* co   = (const float*)d_in[4];
    const float* cmlp = (const float*)d_in[5];
    const float* Wq   = (const float*)d_in[6];
    const float* Wk   = (const float*)d_in[7];
    const float* Wv   = (const float*)d_in[8];
    const float* Wo   = (const float*)d_in[9];
    const float* Wd   = (const float*)d_in[10];
    float* out = (float*)d_out;

    bse_kernel<<<TOTAL_BLOCKS, 256, 0, stream>>>(
        residual, cq, ck, cv, co, cmlp, Wq, Wk, Wv, Wo, Wd, out);
}